// Round 1
// baseline (942.774 us; speedup 1.0000x reference)
//
#include <hip/hip_runtime.h>

// Sizes (fixed by the problem)
#define BB 4
#define CC 256
#define HH 128
#define WW 128
#define HP 64          // pooled H, W
#define NP 4096        // HP*HP tokens per batch
#define OT 320         // q(32) + k(32) + v(256) packed per token

// ---------------------------------------------------------------------------
// K1: 2x2 average pool. x[b][c][128][128] -> xp[b][c][64*64]
// ---------------------------------------------------------------------------
__global__ __launch_bounds__(256) void pool_kernel(const float* __restrict__ x,
                                                   float* __restrict__ xp) {
    int tid = blockIdx.x * 256 + threadIdx.x;      // B*C*NP = 4,194,304 threads
    int wp = tid & 63;
    int hp = (tid >> 6) & 63;
    int bc = tid >> 12;                            // b*C + c
    const float* src = x + (size_t)bc * (HH * WW) + (2 * hp) * WW + 2 * wp;
    float2 a = *(const float2*)(src);
    float2 b = *(const float2*)(src + WW);
    xp[tid] = 0.25f * (a.x + a.y + b.x + b.y);
}

// ---------------------------------------------------------------------------
// K2: fused QKV projection GEMM.
// qkv[b][n][o] = sum_c xp[b][c][n] * W[o][c] + bias[o],  o: 0..31 q, 32..63 k, 64..319 v
// Tiled: 64 n x 64 o per block, K-step 32. 256 threads, 16 outputs/thread.
// ---------------------------------------------------------------------------
__global__ __launch_bounds__(256) void proj_kernel(const float* __restrict__ xp,
    const float* __restrict__ wq, const float* __restrict__ bq,
    const float* __restrict__ wk, const float* __restrict__ bk,
    const float* __restrict__ wv, const float* __restrict__ bv,
    float* __restrict__ qkv) {
    __shared__ float lx[32][64];    // [c][n]
    __shared__ float lwT[32][64];   // [c][o]
    int t = threadIdx.x;
    int ot = blockIdx.x % 5;
    int nt = (blockIdx.x / 5) & 63;
    int b  = blockIdx.x / 320;

    float acc[4][4];
    #pragma unroll
    for (int i = 0; i < 4; i++)
        #pragma unroll
        for (int j = 0; j < 4; j++) acc[i][j] = 0.f;

    int n0 = (t & 15) * 4;
    int o0 = (t >> 4) * 4;

    // staging maps
    int o_l = t >> 2;               // 0..63 weight row
    int og  = ot * 64 + o_l;
    const float* wrow;
    if (og < 32)      wrow = wq + og * CC;
    else if (og < 64) wrow = wk + (og - 32) * CC;
    else              wrow = wv + (og - 64) * CC;
    int c8 = (t & 3) * 8;

    const float* xbase = xp + (size_t)b * CC * NP + nt * 64;
    int cl = t >> 3;                // 0..31
    int nl = (t & 7) * 8;

    for (int c0 = 0; c0 < 256; c0 += 32) {
        const float* xg = xbase + (size_t)(c0 + cl) * NP + nl;
        float4 v0 = *(const float4*)(xg);
        float4 v1 = *(const float4*)(xg + 4);
        float4 w0 = *(const float4*)(wrow + c0 + c8);
        float4 w1 = *(const float4*)(wrow + c0 + c8 + 4);
        __syncthreads();   // previous tile fully consumed before overwrite
        *(float4*)&lx[cl][nl]     = v0;
        *(float4*)&lx[cl][nl + 4] = v1;
        lwT[c8 + 0][o_l] = w0.x; lwT[c8 + 1][o_l] = w0.y;
        lwT[c8 + 2][o_l] = w0.z; lwT[c8 + 3][o_l] = w0.w;
        lwT[c8 + 4][o_l] = w1.x; lwT[c8 + 5][o_l] = w1.y;
        lwT[c8 + 6][o_l] = w1.z; lwT[c8 + 7][o_l] = w1.w;
        __syncthreads();
        #pragma unroll
        for (int cc = 0; cc < 32; cc += 4) {
            float4 xv[4], wv4[4];
            #pragma unroll
            for (int ci = 0; ci < 4; ci++) {
                xv[ci]  = *(const float4*)&lx[cc + ci][n0];
                wv4[ci] = *(const float4*)&lwT[cc + ci][o0];
            }
            #pragma unroll
            for (int ci = 0; ci < 4; ci++) {
                float xn[4] = {xv[ci].x, xv[ci].y, xv[ci].z, xv[ci].w};
                float wo[4] = {wv4[ci].x, wv4[ci].y, wv4[ci].z, wv4[ci].w};
                #pragma unroll
                for (int ni = 0; ni < 4; ni++)
                    #pragma unroll
                    for (int oi = 0; oi < 4; oi++)
                        acc[ni][oi] += xn[ni] * wo[oi];
            }
        }
    }

    float bias[4];
    #pragma unroll
    for (int oi = 0; oi < 4; oi++) {
        int o = ot * 64 + o0 + oi;
        bias[oi] = (o < 32) ? bq[o] : (o < 64) ? bk[o - 32] : bv[o - 64];
    }
    float* obase = qkv + ((size_t)b * NP + nt * 64 + n0) * OT + ot * 64 + o0;
    #pragma unroll
    for (int ni = 0; ni < 4; ni++) {
        float4 r;
        r.x = acc[ni][0] + bias[0];
        r.y = acc[ni][1] + bias[1];
        r.z = acc[ni][2] + bias[2];
        r.w = acc[ni][3] + bias[3];
        *(float4*)(obase + (size_t)ni * OT) = r;
    }
}

// ---------------------------------------------------------------------------
// K3: flash attention. Per block: one batch b, TQ=32 query rows. Iterate all
// 4096 keys in TK=64 chunks with online softmax. att[b][c][n] output (c-major
// so the upsample kernel reads coalesced).
// ---------------------------------------------------------------------------
__global__ __launch_bounds__(256) void flash_kernel(const float* __restrict__ qkv,
                                                    float* __restrict__ att) {
    __shared__ float lq[32][34];
    __shared__ float lk[64][34];
    __shared__ float lp[32][66];
    __shared__ float lmax[32], lsum[32], lscale[32];
    int t  = threadIdx.x;
    int b  = blockIdx.x >> 7;       // /128
    int qt = blockIdx.x & 127;
    const float* qb = qkv + (size_t)b * NP * OT;

    {   // load Q tile [32 rows][32 dims]
        int i = t >> 3, c4 = (t & 7) * 4;
        float4 q4 = *(const float4*)(qb + (size_t)(qt * 32 + i) * OT + c4);
        lq[i][c4 + 0] = q4.x; lq[i][c4 + 1] = q4.y;
        lq[i][c4 + 2] = q4.z; lq[i][c4 + 3] = q4.w;
    }
    if (t < 32) { lmax[t] = -3.0e38f; lsum[t] = 0.f; }

    float acc[4][8];
    #pragma unroll
    for (int i = 0; i < 4; i++)
        #pragma unroll
        for (int j = 0; j < 8; j++) acc[i][j] = 0.f;

    int i0 = (t >> 5) * 4;          // 4 query rows owned
    int c0 = (t & 31) * 8;          // 8 v-channels owned
    int j0 = (t & 31) * 2;          // 2 keys in phase A

    for (int kc = 0; kc < 64; ++kc) {
        int kbase = kc * 64;
        // stage K chunk [64][32] (issue loads before barrier)
        int j1 = t >> 3, c4a = (t & 7) * 4;
        float4 k4a = *(const float4*)(qb + (size_t)(kbase + j1) * OT + 32 + c4a);
        int idx2 = t + 256;
        int j2 = idx2 >> 3, c4b = (idx2 & 7) * 4;
        float4 k4b = *(const float4*)(qb + (size_t)(kbase + j2) * OT + 32 + c4b);
        __syncthreads();   // everyone done with lp of previous chunk
        lk[j1][c4a + 0] = k4a.x; lk[j1][c4a + 1] = k4a.y;
        lk[j1][c4a + 2] = k4a.z; lk[j1][c4a + 3] = k4a.w;
        lk[j2][c4b + 0] = k4b.x; lk[j2][c4b + 1] = k4b.y;
        lk[j2][c4b + 2] = k4b.z; lk[j2][c4b + 3] = k4b.w;
        __syncthreads();

        // phase A: S = Q K^T  (4 rows x 2 keys per thread)
        float s[4][2] = {{0.f,0.f},{0.f,0.f},{0.f,0.f},{0.f,0.f}};
        #pragma unroll 4
        for (int c = 0; c < 32; ++c) {
            float k0 = lk[j0][c], k1 = lk[j0 + 1][c];
            float q0 = lq[i0 + 0][c], q1 = lq[i0 + 1][c];
            float q2 = lq[i0 + 2][c], q3 = lq[i0 + 3][c];
            s[0][0] += q0 * k0; s[0][1] += q0 * k1;
            s[1][0] += q1 * k0; s[1][1] += q1 * k1;
            s[2][0] += q2 * k0; s[2][1] += q2 * k1;
            s[3][0] += q3 * k0; s[3][1] += q3 * k1;
        }
        #pragma unroll
        for (int di = 0; di < 4; di++) {
            lp[i0 + di][j0]     = s[di][0];
            lp[i0 + di][j0 + 1] = s[di][1];
        }
        __syncthreads();

        // phase B: online softmax (8 threads per row)
        {
            int r = t >> 3, jj = t & 7;
            float mloc = -3.0e38f;
            #pragma unroll
            for (int k8 = 0; k8 < 8; ++k8) mloc = fmaxf(mloc, lp[r][jj + 8 * k8]);
            #pragma unroll
            for (int d = 1; d < 8; d <<= 1) mloc = fmaxf(mloc, __shfl_xor(mloc, d, 64));
            float mold = lmax[r];
            float mnew = fmaxf(mold, mloc);
            float sc = __expf(mold - mnew);   // 0 on first chunk (mold=-inf)
            float ssum = 0.f;
            #pragma unroll
            for (int k8 = 0; k8 < 8; ++k8) {
                int j = jj + 8 * k8;
                float p = __expf(lp[r][j] - mnew);
                lp[r][j] = p;
                ssum += p;
            }
            #pragma unroll
            for (int d = 1; d < 8; d <<= 1) ssum += __shfl_xor(ssum, d, 64);
            if (jj == 0) {
                lmax[r]   = mnew;
                lsum[r]   = lsum[r] * sc + ssum;
                lscale[r] = sc;
            }
        }
        __syncthreads();

        // phase C: rescale acc, accumulate P·V (V streamed from L2/L3)
        {
            float rs[4];
            #pragma unroll
            for (int di = 0; di < 4; di++) rs[di] = lscale[i0 + di];
            #pragma unroll
            for (int di = 0; di < 4; di++)
                #pragma unroll
                for (int dc = 0; dc < 8; dc++) acc[di][dc] *= rs[di];

            const float* vb = qb + (size_t)kbase * OT + 64 + c0;
            #pragma unroll 2
            for (int j = 0; j < 64; ++j) {
                float p0 = lp[i0 + 0][j], p1 = lp[i0 + 1][j];
                float p2 = lp[i0 + 2][j], p3 = lp[i0 + 3][j];
                float4 va  = *(const float4*)(vb + (size_t)j * OT);
                float4 vb4 = *(const float4*)(vb + (size_t)j * OT + 4);
                float vv[8] = {va.x, va.y, va.z, va.w, vb4.x, vb4.y, vb4.z, vb4.w};
                #pragma unroll
                for (int dc = 0; dc < 8; dc++) {
                    acc[0][dc] += p0 * vv[dc];
                    acc[1][dc] += p1 * vv[dc];
                    acc[2][dc] += p2 * vv[dc];
                    acc[3][dc] += p3 * vv[dc];
                }
            }
        }
        __syncthreads();
    }

    // epilogue: normalize and write att[b][c][n]
    float linv[4];
    #pragma unroll
    for (int di = 0; di < 4; di++) linv[di] = 1.0f / lsum[i0 + di];
    #pragma unroll
    for (int dc = 0; dc < 8; dc++) {
        int c = c0 + dc;
        float* ob = att + ((size_t)(b * CC + c)) * NP + qt * 32;
        #pragma unroll
        for (int di = 0; di < 4; di++) ob[i0 + di] = acc[di][dc] * linv[di];
    }
}

// ---------------------------------------------------------------------------
// K4: bilinear x2 upsample (half-pixel, edge clamp) + gamma * up + x
// ---------------------------------------------------------------------------
__global__ __launch_bounds__(256) void upsample_kernel(const float* __restrict__ att,
                                                       const float* __restrict__ x,
                                                       const float* __restrict__ gamma,
                                                       float* __restrict__ out) {
    int tid = blockIdx.x * 256 + threadIdx.x;    // B*C*H*W
    int w = tid & 127;
    int h = (tid >> 7) & 127;
    int bc = tid >> 14;
    float g = gamma[0];
    float sh = 0.5f * h - 0.25f;
    float sw = 0.5f * w - 0.25f;
    float fhf = floorf(sh), fwf = floorf(sw);
    float th = sh - fhf, tw = sw - fwf;
    int ih = (int)fhf, iw = (int)fwf;
    int ih0 = ih < 0 ? 0 : ih;
    int ih1 = ih + 1 > 63 ? 63 : ih + 1;
    int iw0 = iw < 0 ? 0 : iw;
    int iw1 = iw + 1 > 63 ? 63 : iw + 1;
    const float* a = att + (size_t)bc * NP;
    float v00 = a[ih0 * 64 + iw0], v01 = a[ih0 * 64 + iw1];
    float v10 = a[ih1 * 64 + iw0], v11 = a[ih1 * 64 + iw1];
    float top = v00 + tw * (v01 - v00);
    float bot = v10 + tw * (v11 - v10);
    float up  = top + th * (bot - top);
    out[tid] = g * up + x[tid];
}

// ---------------------------------------------------------------------------
extern "C" void kernel_launch(void* const* d_in, const int* in_sizes, int n_in,
                              void* d_out, int out_size, void* d_ws, size_t ws_size,
                              hipStream_t stream) {
    (void)in_sizes; (void)n_in; (void)out_size; (void)ws_size;
    const float* x     = (const float*)d_in[0];
    const float* wq    = (const float*)d_in[1];
    const float* bq    = (const float*)d_in[2];
    const float* wk    = (const float*)d_in[3];
    const float* bk    = (const float*)d_in[4];
    const float* wv    = (const float*)d_in[5];
    const float* bv    = (const float*)d_in[6];
    const float* gamma = (const float*)d_in[7];
    float* out = (float*)d_out;
    float* ws  = (float*)d_ws;

    float* xp  = ws;                 // B*C*NP      = 4,194,304 floats
    float* qkv = ws + 4194304;       // B*NP*OT     = 5,242,880 floats
    float* att = ws + 9437184;       // B*C*NP      = 4,194,304 floats
                                     // total 13,631,488 floats = 54.5 MB

    pool_kernel<<<16384, 256, 0, stream>>>(x, xp);
    proj_kernel<<<1280, 256, 0, stream>>>(xp, wq, bq, wk, bk, wv, bv, qkv);
    flash_kernel<<<512, 256, 0, stream>>>(qkv, att);
    upsample_kernel<<<65536, 256, 0, stream>>>(att, x, gamma, out);
}

// Round 2
// 394.369 us; speedup vs baseline: 2.3906x; 2.3906x over previous
//
#include <hip/hip_runtime.h>

// Sizes (fixed by the problem)
#define BB 4
#define CC 256
#define HH 128
#define WW 128
#define HP 64          // pooled H, W
#define NP 4096        // HP*HP tokens per batch

typedef __attribute__((ext_vector_type(4))) float f32x4;
typedef __attribute__((ext_vector_type(8))) short bf16x8;   // 8 bf16 in 4 VGPRs

// float -> bf16 bits, round-to-nearest-even (finite inputs only)
static __device__ __forceinline__ unsigned short f2bf(float f) {
    unsigned int u = __float_as_uint(f);
    u = (u + 0x7FFFu + ((u >> 16) & 1u)) >> 16;
    return (unsigned short)u;
}

// ---------------------------------------------------------------------------
// K1: 2x2 average pool. x[b][c][128][128] -> xp[b][c][64*64]
// ---------------------------------------------------------------------------
__global__ __launch_bounds__(256) void pool_kernel(const float* __restrict__ x,
                                                   float* __restrict__ xp) {
    int tid = blockIdx.x * 256 + threadIdx.x;      // B*C*NP threads
    int wp = tid & 63;
    int hp = (tid >> 6) & 63;
    int bc = tid >> 12;
    const float* src = x + (size_t)bc * (HH * WW) + (2 * hp) * WW + 2 * wp;
    float2 a = *(const float2*)(src);
    float2 b = *(const float2*)(src + WW);
    xp[tid] = 0.25f * (a.x + a.y + b.x + b.y);
}

// ---------------------------------------------------------------------------
// K2: fused QKV projection GEMM (fp32 math), bf16 outputs in two layouts:
//   qk[b][n][64]  : o 0..31 = q, 32..63 = k   (token-major, for QK^T frags)
//   vt[b][c][n]   : c 0..255                  (channel-major, for PV B frags)
// ---------------------------------------------------------------------------
__global__ __launch_bounds__(256) void proj_kernel(const float* __restrict__ xp,
    const float* __restrict__ wq, const float* __restrict__ bq,
    const float* __restrict__ wk, const float* __restrict__ bk,
    const float* __restrict__ wv, const float* __restrict__ bv,
    unsigned short* __restrict__ qk, unsigned short* __restrict__ vt) {
    __shared__ float lx[32][64];    // [c][n]
    __shared__ float lwT[32][64];   // [c][o]
    int t = threadIdx.x;
    int ot = blockIdx.x % 5;
    int nt = (blockIdx.x / 5) & 63;
    int b  = blockIdx.x / 320;

    float acc[4][4];
    #pragma unroll
    for (int i = 0; i < 4; i++)
        #pragma unroll
        for (int j = 0; j < 4; j++) acc[i][j] = 0.f;

    int n0 = (t & 15) * 4;
    int o0 = (t >> 4) * 4;

    int o_l = t >> 2;               // 0..63 weight row
    int og  = ot * 64 + o_l;
    const float* wrow;
    if (og < 32)      wrow = wq + og * CC;
    else if (og < 64) wrow = wk + (og - 32) * CC;
    else              wrow = wv + (og - 64) * CC;
    int c8 = (t & 3) * 8;

    const float* xbase = xp + (size_t)b * CC * NP + nt * 64;
    int cl = t >> 3;                // 0..31
    int nl = (t & 7) * 8;

    for (int c0 = 0; c0 < 256; c0 += 32) {
        const float* xg = xbase + (size_t)(c0 + cl) * NP + nl;
        float4 v0 = *(const float4*)(xg);
        float4 v1 = *(const float4*)(xg + 4);
        float4 w0 = *(const float4*)(wrow + c0 + c8);
        float4 w1 = *(const float4*)(wrow + c0 + c8 + 4);
        __syncthreads();
        *(float4*)&lx[cl][nl]     = v0;
        *(float4*)&lx[cl][nl + 4] = v1;
        lwT[c8 + 0][o_l] = w0.x; lwT[c8 + 1][o_l] = w0.y;
        lwT[c8 + 2][o_l] = w0.z; lwT[c8 + 3][o_l] = w0.w;
        lwT[c8 + 4][o_l] = w1.x; lwT[c8 + 5][o_l] = w1.y;
        lwT[c8 + 6][o_l] = w1.z; lwT[c8 + 7][o_l] = w1.w;
        __syncthreads();
        #pragma unroll
        for (int cc = 0; cc < 32; cc += 4) {
            float4 xv[4], wv4[4];
            #pragma unroll
            for (int ci = 0; ci < 4; ci++) {
                xv[ci]  = *(const float4*)&lx[cc + ci][n0];
                wv4[ci] = *(const float4*)&lwT[cc + ci][o0];
            }
            #pragma unroll
            for (int ci = 0; ci < 4; ci++) {
                float xn[4] = {xv[ci].x, xv[ci].y, xv[ci].z, xv[ci].w};
                float wo[4] = {wv4[ci].x, wv4[ci].y, wv4[ci].z, wv4[ci].w};
                #pragma unroll
                for (int ni = 0; ni < 4; ni++)
                    #pragma unroll
                    for (int oi = 0; oi < 4; oi++)
                        acc[ni][oi] += xn[ni] * wo[oi];
            }
        }
    }

    float bias[4];
    #pragma unroll
    for (int oi = 0; oi < 4; oi++) {
        int o = ot * 64 + o0 + oi;
        bias[oi] = (o < 32) ? bq[o] : (o < 64) ? bk[o - 32] : bv[o - 64];
    }

    if (ot == 0) {
        // qk[b][n][o], 4 consecutive o per n -> 8B stores
        #pragma unroll
        for (int ni = 0; ni < 4; ni++) {
            ushort4 r;
            r.x = f2bf(acc[ni][0] + bias[0]);
            r.y = f2bf(acc[ni][1] + bias[1]);
            r.z = f2bf(acc[ni][2] + bias[2]);
            r.w = f2bf(acc[ni][3] + bias[3]);
            int n = nt * 64 + n0 + ni;
            *(ushort4*)(qk + ((size_t)b * NP + n) * 64 + o0) = r;
        }
    } else {
        // vt[b][c][n], 4 consecutive n per c -> 8B stores
        #pragma unroll
        for (int oi = 0; oi < 4; oi++) {
            int c = ot * 64 + o0 + oi - 64;
            ushort4 r;
            r.x = f2bf(acc[0][oi] + bias[oi]);
            r.y = f2bf(acc[1][oi] + bias[oi]);
            r.z = f2bf(acc[2][oi] + bias[oi]);
            r.w = f2bf(acc[3][oi] + bias[oi]);
            *(ushort4*)(vt + ((size_t)b * CC + c) * NP + nt * 64 + n0) = r;
        }
    }
}

// ---------------------------------------------------------------------------
// K3: MFMA flash attention. One wave owns 16 q-rows, iterates 4096 keys in
// 64-key chunks with online softmax. 4 independent waves per block, no
// block barriers. Output att[b][c][n] fp32 (normalized).
//
// mfma_f32_16x16x32_bf16 layouts (per guide §3, m89-verified):
//   A: row = lane&15, k = (lane>>4)*8 + e   (8 contiguous bf16 / lane)
//   B: col = lane&15, k = (lane>>4)*8 + e
//   D: col = lane&15, row = (lane>>4)*4 + reg
// ---------------------------------------------------------------------------
__global__ __launch_bounds__(256) void flashm_kernel(const unsigned short* __restrict__ qk,
                                                     const unsigned short* __restrict__ vt,
                                                     float* __restrict__ att) {
    __shared__ char p_lds[4][2048];   // per wave: P tile 16 rows x 64 keys bf16, XOR-swizzled
    int t    = threadIdx.x;
    int lane = t & 63;
    int w    = t >> 6;
    int wid  = blockIdx.x * 4 + w;
    int b    = wid >> 8;              // 256 q-tiles per batch
    int qt   = wid & 255;

    const unsigned short* qkb = qk + (size_t)b * NP * 64;
    const unsigned short* vtb = vt + (size_t)b * CC * NP;
    char* pl = p_lds[w];

    int lr = lane & 15;
    int lg = lane >> 4;

    // Q A-fragment: row qt*16+lr, channels lg*8..+7 (held for the whole kernel)
    bf16x8 qf = *(const bf16x8*)(qkb + ((size_t)(qt * 16 + lr)) * 64 + lg * 8);

    f32x4 acc[16];
    #pragma unroll
    for (int i = 0; i < 16; i++) acc[i] = (f32x4){0.f, 0.f, 0.f, 0.f};
    float mrun[4] = {-3.0e38f, -3.0e38f, -3.0e38f, -3.0e38f};
    float lrun[4] = {0.f, 0.f, 0.f, 0.f};

    for (int kc = 0; kc < 64; ++kc) {
        int kbase = kc * 64;

        // ---- QK^T: 4 MFMA -> S[16 q][64 keys]
        f32x4 s[4];
        #pragma unroll
        for (int kt = 0; kt < 4; kt++) {
            bf16x8 kf = *(const bf16x8*)(qkb + ((size_t)(kbase + kt * 16 + lr)) * 64 + 32 + lg * 8);
            s[kt] = __builtin_amdgcn_mfma_f32_16x16x32_bf16(qf, kf,
                        (f32x4){0.f, 0.f, 0.f, 0.f}, 0, 0, 0);
        }

        // ---- online softmax (rows live in 16-lane groups; reduce via shfl_xor)
        float mx[4];
        #pragma unroll
        for (int r = 0; r < 4; r++)
            mx[r] = fmaxf(fmaxf(s[0][r], s[1][r]), fmaxf(s[2][r], s[3][r]));
        #pragma unroll
        for (int d = 1; d < 16; d <<= 1)
            #pragma unroll
            for (int r = 0; r < 4; r++)
                mx[r] = fmaxf(mx[r], __shfl_xor(mx[r], d, 64));

        float sc[4];
        #pragma unroll
        for (int r = 0; r < 4; r++) {
            float mnew = fmaxf(mrun[r], mx[r]);
            sc[r]   = __expf(mrun[r] - mnew);
            mrun[r] = mnew;
        }

        float ps[4] = {0.f, 0.f, 0.f, 0.f};
        #pragma unroll
        for (int kt = 0; kt < 4; kt++) {
            #pragma unroll
            for (int r = 0; r < 4; r++) {
                float p = __expf(s[kt][r] - mrun[r]);
                ps[r] += p;
                int row = lg * 4 + r;
                int key = kt * 16 + lr;
                int off = (row * 128 + key * 2) ^ ((row & 7) << 4);  // XOR swizzle
                *(unsigned short*)(pl + off) = f2bf(p);
            }
        }
        #pragma unroll
        for (int d = 1; d < 16; d <<= 1)
            #pragma unroll
            for (int r = 0; r < 4; r++)
                ps[r] += __shfl_xor(ps[r], d, 64);
        #pragma unroll
        for (int r = 0; r < 4; r++) lrun[r] = lrun[r] * sc[r] + ps[r];

        // rescale accumulator
        #pragma unroll
        for (int ct = 0; ct < 16; ct++)
            #pragma unroll
            for (int r = 0; r < 4; r++) acc[ct][r] *= sc[r];

        // make this wave's P writes visible to its own cross-lane reads
        asm volatile("s_waitcnt lgkmcnt(0)" ::: "memory");
        __builtin_amdgcn_sched_barrier(0);

        // ---- PV: 2 K-steps x 16 channel tiles = 32 MFMA
        #pragma unroll
        for (int kt2 = 0; kt2 < 2; kt2++) {
            int roff = (lr * 128 + (kt2 * 32 + lg * 8) * 2) ^ ((lr & 7) << 4);
            bf16x8 pf = *(const bf16x8*)(pl + roff);
            const unsigned short* vb = vtb + kbase + kt2 * 32 + lg * 8;
            #pragma unroll
            for (int ct = 0; ct < 16; ct++) {
                bf16x8 vf = *(const bf16x8*)(vb + (size_t)(ct * 16 + lr) * NP);
                acc[ct] = __builtin_amdgcn_mfma_f32_16x16x32_bf16(pf, vf, acc[ct], 0, 0, 0);
            }
        }
    }

    // ---- epilogue: normalize, store att[b][c][n] as float4 (4 consecutive n)
    float inv[4];
    #pragma unroll
    for (int r = 0; r < 4; r++) inv[r] = 1.0f / lrun[r];
    #pragma unroll
    for (int ct = 0; ct < 16; ct++) {
        float4 o;
        o.x = acc[ct][0] * inv[0];
        o.y = acc[ct][1] * inv[1];
        o.z = acc[ct][2] * inv[2];
        o.w = acc[ct][3] * inv[3];
        int c = ct * 16 + lr;
        *(float4*)(att + ((size_t)b * CC + c) * NP + qt * 16 + lg * 4) = o;
    }
}

// ---------------------------------------------------------------------------
// K4: bilinear x2 upsample (half-pixel, edge clamp) + gamma * up + x
// ---------------------------------------------------------------------------
__global__ __launch_bounds__(256) void upsample_kernel(const float* __restrict__ att,
                                                       const float* __restrict__ x,
                                                       const float* __restrict__ gamma,
                                                       float* __restrict__ out) {
    int tid = blockIdx.x * 256 + threadIdx.x;    // B*C*H*W
    int w = tid & 127;
    int h = (tid >> 7) & 127;
    int bc = tid >> 14;
    float g = gamma[0];
    float sh = 0.5f * h - 0.25f;
    float sw = 0.5f * w - 0.25f;
    float fhf = floorf(sh), fwf = floorf(sw);
    float th = sh - fhf, tw = sw - fwf;
    int ih = (int)fhf, iw = (int)fwf;
    int ih0 = ih < 0 ? 0 : ih;
    int ih1 = ih + 1 > 63 ? 63 : ih + 1;
    int iw0 = iw < 0 ? 0 : iw;
    int iw1 = iw + 1 > 63 ? 63 : iw + 1;
    const float* a = att + (size_t)bc * NP;
    float v00 = a[ih0 * 64 + iw0], v01 = a[ih0 * 64 + iw1];
    float v10 = a[ih1 * 64 + iw0], v11 = a[ih1 * 64 + iw1];
    float top = v00 + tw * (v01 - v00);
    float bot = v10 + tw * (v11 - v10);
    float up  = top + th * (bot - top);
    out[tid] = g * up + x[tid];
}

// ---------------------------------------------------------------------------
extern "C" void kernel_launch(void* const* d_in, const int* in_sizes, int n_in,
                              void* d_out, int out_size, void* d_ws, size_t ws_size,
                              hipStream_t stream) {
    (void)in_sizes; (void)n_in; (void)out_size; (void)ws_size;
    const float* x     = (const float*)d_in[0];
    const float* wq    = (const float*)d_in[1];
    const float* bq    = (const float*)d_in[2];
    const float* wk    = (const float*)d_in[3];
    const float* bk    = (const float*)d_in[4];
    const float* wv    = (const float*)d_in[5];
    const float* bv    = (const float*)d_in[6];
    const float* gamma = (const float*)d_in[7];
    float* out = (float*)d_out;
    float* ws  = (float*)d_ws;

    float*          xp  = ws;                                  // 4,194,304 f32 (16 MB)
    unsigned short* qkb = (unsigned short*)(ws + 4194304);     // 4*4096*64  bf16 (2 MB)
    unsigned short* vtb = qkb + 1048576;                       // 4*256*4096 bf16 (8 MB)
    float*          att = (float*)(vtb + 4194304);             // 4,194,304 f32 (16 MB)
                                                               // total 42 MB

    pool_kernel<<<16384, 256, 0, stream>>>(x, xp);
    proj_kernel<<<1280, 256, 0, stream>>>(xp, wq, bq, wk, bk, wv, bv, qkb, vtb);
    flashm_kernel<<<256, 256, 0, stream>>>(qkb, vtb, att);
    upsample_kernel<<<65536, 256, 0, stream>>>(att, x, gamma, out);
}

// Round 3
// 349.990 us; speedup vs baseline: 2.6937x; 1.1268x over previous
//
#include <hip/hip_runtime.h>

// Sizes (fixed by the problem)
#define BB 4
#define CC 256
#define HH 128
#define WW 128
#define HP 64          // pooled H, W
#define NP 4096        // HP*HP tokens per batch

typedef __attribute__((ext_vector_type(4))) float f32x4;
typedef __attribute__((ext_vector_type(8))) short bf16x8;   // 8 bf16 in 4 VGPRs

// float -> bf16 bits, round-to-nearest-even (finite inputs only)
static __device__ __forceinline__ unsigned short f2bf(float f) {
    unsigned int u = __float_as_uint(f);
    u = (u + 0x7FFFu + ((u >> 16) & 1u)) >> 16;
    return (unsigned short)u;
}

// ---------------------------------------------------------------------------
// K1: 2x2 average pool. x[b][c][128][128] -> xp[b][c][64*64]
// ---------------------------------------------------------------------------
__global__ __launch_bounds__(256) void pool_kernel(const float* __restrict__ x,
                                                   float* __restrict__ xp) {
    int tid = blockIdx.x * 256 + threadIdx.x;      // B*C*NP threads
    int wp = tid & 63;
    int hp = (tid >> 6) & 63;
    int bc = tid >> 12;
    const float* src = x + (size_t)bc * (HH * WW) + (2 * hp) * WW + 2 * wp;
    float2 a = *(const float2*)(src);
    float2 b = *(const float2*)(src + WW);
    xp[tid] = 0.25f * (a.x + a.y + b.x + b.y);
}

// ---------------------------------------------------------------------------
// K2: fused QKV projection GEMM (fp32 math), bf16 outputs in two layouts:
//   qk[b][n][64]  : o 0..31 = q, 32..63 = k   (token-major, for QK^T frags)
//   vt[b][c][n]   : c 0..255                  (channel-major, for PV B frags)
// ---------------------------------------------------------------------------
__global__ __launch_bounds__(256) void proj_kernel(const float* __restrict__ xp,
    const float* __restrict__ wq, const float* __restrict__ bq,
    const float* __restrict__ wk, const float* __restrict__ bk,
    const float* __restrict__ wv, const float* __restrict__ bv,
    unsigned short* __restrict__ qk, unsigned short* __restrict__ vt) {
    __shared__ float lx[32][64];    // [c][n]
    __shared__ float lwT[32][64];   // [c][o]
    int t = threadIdx.x;
    int ot = blockIdx.x % 5;
    int nt = (blockIdx.x / 5) & 63;
    int b  = blockIdx.x / 320;

    float acc[4][4];
    #pragma unroll
    for (int i = 0; i < 4; i++)
        #pragma unroll
        for (int j = 0; j < 4; j++) acc[i][j] = 0.f;

    int n0 = (t & 15) * 4;
    int o0 = (t >> 4) * 4;

    int o_l = t >> 2;               // 0..63 weight row
    int og  = ot * 64 + o_l;
    const float* wrow;
    if (og < 32)      wrow = wq + og * CC;
    else if (og < 64) wrow = wk + (og - 32) * CC;
    else              wrow = wv + (og - 64) * CC;
    int c8 = (t & 3) * 8;

    const float* xbase = xp + (size_t)b * CC * NP + nt * 64;
    int cl = t >> 3;                // 0..31
    int nl = (t & 7) * 8;

    for (int c0 = 0; c0 < 256; c0 += 32) {
        const float* xg = xbase + (size_t)(c0 + cl) * NP + nl;
        float4 v0 = *(const float4*)(xg);
        float4 v1 = *(const float4*)(xg + 4);
        float4 w0 = *(const float4*)(wrow + c0 + c8);
        float4 w1 = *(const float4*)(wrow + c0 + c8 + 4);
        __syncthreads();
        *(float4*)&lx[cl][nl]     = v0;
        *(float4*)&lx[cl][nl + 4] = v1;
        lwT[c8 + 0][o_l] = w0.x; lwT[c8 + 1][o_l] = w0.y;
        lwT[c8 + 2][o_l] = w0.z; lwT[c8 + 3][o_l] = w0.w;
        lwT[c8 + 4][o_l] = w1.x; lwT[c8 + 5][o_l] = w1.y;
        lwT[c8 + 6][o_l] = w1.z; lwT[c8 + 7][o_l] = w1.w;
        __syncthreads();
        #pragma unroll
        for (int cc = 0; cc < 32; cc += 4) {
            float4 xv[4], wv4[4];
            #pragma unroll
            for (int ci = 0; ci < 4; ci++) {
                xv[ci]  = *(const float4*)&lx[cc + ci][n0];
                wv4[ci] = *(const float4*)&lwT[cc + ci][o0];
            }
            #pragma unroll
            for (int ci = 0; ci < 4; ci++) {
                float xn[4] = {xv[ci].x, xv[ci].y, xv[ci].z, xv[ci].w};
                float wo[4] = {wv4[ci].x, wv4[ci].y, wv4[ci].z, wv4[ci].w};
                #pragma unroll
                for (int ni = 0; ni < 4; ni++)
                    #pragma unroll
                    for (int oi = 0; oi < 4; oi++)
                        acc[ni][oi] += xn[ni] * wo[oi];
            }
        }
    }

    float bias[4];
    #pragma unroll
    for (int oi = 0; oi < 4; oi++) {
        int o = ot * 64 + o0 + oi;
        bias[oi] = (o < 32) ? bq[o] : (o < 64) ? bk[o - 32] : bv[o - 64];
    }

    if (ot == 0) {
        #pragma unroll
        for (int ni = 0; ni < 4; ni++) {
            ushort4 r;
            r.x = f2bf(acc[ni][0] + bias[0]);
            r.y = f2bf(acc[ni][1] + bias[1]);
            r.z = f2bf(acc[ni][2] + bias[2]);
            r.w = f2bf(acc[ni][3] + bias[3]);
            int n = nt * 64 + n0 + ni;
            *(ushort4*)(qk + ((size_t)b * NP + n) * 64 + o0) = r;
        }
    } else {
        #pragma unroll
        for (int oi = 0; oi < 4; oi++) {
            int c = ot * 64 + o0 + oi - 64;
            ushort4 r;
            r.x = f2bf(acc[0][oi] + bias[oi]);
            r.y = f2bf(acc[1][oi] + bias[oi]);
            r.z = f2bf(acc[2][oi] + bias[oi]);
            r.w = f2bf(acc[3][oi] + bias[oi]);
            *(ushort4*)(vt + ((size_t)b * CC + c) * NP + nt * 64 + n0) = r;
        }
    }
}

// ---------------------------------------------------------------------------
// K3: MFMA flash attention, split-K x4.
// One block = one 16-row q-tile. Wave w handles key chunks [w*16, w*16+16)
// (1024 keys each) with an independent online-softmax state; states merged
// elementwise through LDS at the end (same lane = same (c, q-row) element in
// every wave). Grid = 1024 blocks -> 4 blocks/CU, 16 waves/CU.
//
// mfma_f32_16x16x32_bf16 layouts (m89-verified):
//   A: row = lane&15, k = (lane>>4)*8 + e
//   B: col = lane&15, k = (lane>>4)*8 + e
//   D: col = lane&15, row = (lane>>4)*4 + reg
// ---------------------------------------------------------------------------
__global__ __launch_bounds__(256) void flashm_kernel(const unsigned short* __restrict__ qk,
                                                     const unsigned short* __restrict__ vt,
                                                     float* __restrict__ att) {
    __shared__ char  p_lds[4][2048];  // per wave: P tile 16 rows x 64 keys bf16, XOR-swizzled
    __shared__ float cacc[64][68];    // combine: one wave's acc (64 lanes x 64 f32), padded rows
    __shared__ float cml[64][8];      // combine: m[4], l[4] per lane
    int t    = threadIdx.x;
    int lane = t & 63;
    int w    = t >> 6;
    int b    = blockIdx.x >> 8;       // 256 q-tiles per batch
    int qt   = blockIdx.x & 255;

    const unsigned short* qkb = qk + (size_t)b * NP * 64;
    const unsigned short* vtb = vt + (size_t)b * CC * NP;
    char* pl = p_lds[w];

    int lr = lane & 15;
    int lg = lane >> 4;

    // Q A-fragment: row qt*16+lr, channels lg*8..+7 (held for the whole kernel)
    bf16x8 qf = *(const bf16x8*)(qkb + ((size_t)(qt * 16 + lr)) * 64 + lg * 8);

    f32x4 acc[16];
    #pragma unroll
    for (int i = 0; i < 16; i++) acc[i] = (f32x4){0.f, 0.f, 0.f, 0.f};
    float mrun[4] = {-3.0e38f, -3.0e38f, -3.0e38f, -3.0e38f};
    float lrun[4] = {0.f, 0.f, 0.f, 0.f};

    for (int kc = w * 16; kc < w * 16 + 16; ++kc) {
        int kbase = kc * 64;

        // ---- QK^T: 4 MFMA -> S[16 q][64 keys]
        f32x4 s[4];
        #pragma unroll
        for (int kt = 0; kt < 4; kt++) {
            bf16x8 kf = *(const bf16x8*)(qkb + ((size_t)(kbase + kt * 16 + lr)) * 64 + 32 + lg * 8);
            s[kt] = __builtin_amdgcn_mfma_f32_16x16x32_bf16(qf, kf,
                        (f32x4){0.f, 0.f, 0.f, 0.f}, 0, 0, 0);
        }

        // ---- chunk max (rows live in 16-lane groups; reduce via shfl_xor)
        float mx[4];
        #pragma unroll
        for (int r = 0; r < 4; r++)
            mx[r] = fmaxf(fmaxf(s[0][r], s[1][r]), fmaxf(s[2][r], s[3][r]));
        #pragma unroll
        for (int d = 1; d < 16; d <<= 1)
            #pragma unroll
            for (int r = 0; r < 4; r++)
                mx[r] = fmaxf(mx[r], __shfl_xor(mx[r], d, 64));

        // ---- defer-max (T13): only rescale when the max grew by > 8
        float need = mx[0] - mrun[0];
        #pragma unroll
        for (int r = 1; r < 4; r++) need = fmaxf(need, mx[r] - mrun[r]);
        if (!__all(need <= 8.0f)) {
            float sc[4];
            #pragma unroll
            for (int r = 0; r < 4; r++) {
                float mnew = fmaxf(mrun[r], mx[r]);
                sc[r]   = __expf(mrun[r] - mnew);
                mrun[r] = mnew;
                lrun[r] *= sc[r];
            }
            #pragma unroll
            for (int ct = 0; ct < 16; ct++)
                #pragma unroll
                for (int r = 0; r < 4; r++) acc[ct][r] *= sc[r];
        }

        // ---- P = exp(S - m), P-sum, P -> LDS (bf16, XOR-swizzled)
        float ps[4] = {0.f, 0.f, 0.f, 0.f};
        #pragma unroll
        for (int kt = 0; kt < 4; kt++) {
            #pragma unroll
            for (int r = 0; r < 4; r++) {
                float p = __expf(s[kt][r] - mrun[r]);
                ps[r] += p;
                int row = lg * 4 + r;
                int key = kt * 16 + lr;
                int off = (row * 128 + key * 2) ^ ((row & 7) << 4);
                *(unsigned short*)(pl + off) = f2bf(p);
            }
        }
        #pragma unroll
        for (int d = 1; d < 16; d <<= 1)
            #pragma unroll
            for (int r = 0; r < 4; r++)
                ps[r] += __shfl_xor(ps[r], d, 64);
        #pragma unroll
        for (int r = 0; r < 4; r++) lrun[r] += ps[r];

        // make this wave's P writes visible to its own cross-lane reads
        asm volatile("s_waitcnt lgkmcnt(0)" ::: "memory");
        __builtin_amdgcn_sched_barrier(0);

        // ---- PV: 2 K-steps x 16 channel tiles = 32 MFMA
        #pragma unroll
        for (int kt2 = 0; kt2 < 2; kt2++) {
            int roff = (lr * 128 + (kt2 * 32 + lg * 8) * 2) ^ ((lr & 7) << 4);
            bf16x8 pf = *(const bf16x8*)(pl + roff);
            const unsigned short* vb = vtb + kbase + kt2 * 32 + lg * 8;
            #pragma unroll
            for (int ct = 0; ct < 16; ct++) {
                bf16x8 vf = *(const bf16x8*)(vb + (size_t)(ct * 16 + lr) * NP);
                acc[ct] = __builtin_amdgcn_mfma_f32_16x16x32_bf16(pf, vf, acc[ct], 0, 0, 0);
            }
        }
    }

    // ---- split-K combine: waves 3,2,1 hand state to wave 0 (elementwise per lane)
    for (int s = 3; s >= 1; --s) {
        if (w == s) {
            #pragma unroll
            for (int ct = 0; ct < 16; ct++) *(f32x4*)&cacc[lane][ct * 4] = acc[ct];
            #pragma unroll
            for (int r = 0; r < 4; r++) { cml[lane][r] = mrun[r]; cml[lane][4 + r] = lrun[r]; }
        }
        __syncthreads();
        if (w == 0) {
            float e0[4], e1[4];
            #pragma unroll
            for (int r = 0; r < 4; r++) {
                float mo = cml[lane][r];
                float lo = cml[lane][4 + r];
                float mn = fmaxf(mrun[r], mo);
                e0[r] = __expf(mrun[r] - mn);
                e1[r] = __expf(mo - mn);
                mrun[r] = mn;
                lrun[r] = lrun[r] * e0[r] + lo * e1[r];
            }
            #pragma unroll
            for (int ct = 0; ct < 16; ct++) {
                f32x4 o = *(const f32x4*)&cacc[lane][ct * 4];
                #pragma unroll
                for (int r = 0; r < 4; r++)
                    acc[ct][r] = acc[ct][r] * e0[r] + o[r] * e1[r];
            }
        }
        __syncthreads();
    }

    if (w == 0) {
        float inv[4];
        #pragma unroll
        for (int r = 0; r < 4; r++) inv[r] = 1.0f / lrun[r];
        #pragma unroll
        for (int ct = 0; ct < 16; ct++) {
            float4 o;
            o.x = acc[ct][0] * inv[0];
            o.y = acc[ct][1] * inv[1];
            o.z = acc[ct][2] * inv[2];
            o.w = acc[ct][3] * inv[3];
            int c = ct * 16 + lr;
            *(float4*)(att + ((size_t)b * CC + c) * NP + qt * 16 + lg * 4) = o;
        }
    }
}

// ---------------------------------------------------------------------------
// K4: bilinear x2 upsample (half-pixel, edge clamp) + gamma * up + x
// ---------------------------------------------------------------------------
__global__ __launch_bounds__(256) void upsample_kernel(const float* __restrict__ att,
                                                       const float* __restrict__ x,
                                                       const float* __restrict__ gamma,
                                                       float* __restrict__ out) {
    int tid = blockIdx.x * 256 + threadIdx.x;    // B*C*H*W
    int w = tid & 127;
    int h = (tid >> 7) & 127;
    int bc = tid >> 14;
    float g = gamma[0];
    float sh = 0.5f * h - 0.25f;
    float sw = 0.5f * w - 0.25f;
    float fhf = floorf(sh), fwf = floorf(sw);
    float th = sh - fhf, tw = sw - fwf;
    int ih = (int)fhf, iw = (int)fwf;
    int ih0 = ih < 0 ? 0 : ih;
    int ih1 = ih + 1 > 63 ? 63 : ih + 1;
    int iw0 = iw < 0 ? 0 : iw;
    int iw1 = iw + 1 > 63 ? 63 : iw + 1;
    const float* a = att + (size_t)bc * NP;
    float v00 = a[ih0 * 64 + iw0], v01 = a[ih0 * 64 + iw1];
    float v10 = a[ih1 * 64 + iw0], v11 = a[ih1 * 64 + iw1];
    float top = v00 + tw * (v01 - v00);
    float bot = v10 + tw * (v11 - v10);
    float up  = top + th * (bot - top);
    out[tid] = g * up + x[tid];
}

// ---------------------------------------------------------------------------
extern "C" void kernel_launch(void* const* d_in, const int* in_sizes, int n_in,
                              void* d_out, int out_size, void* d_ws, size_t ws_size,
                              hipStream_t stream) {
    (void)in_sizes; (void)n_in; (void)out_size; (void)ws_size;
    const float* x     = (const float*)d_in[0];
    const float* wq    = (const float*)d_in[1];
    const float* bq    = (const float*)d_in[2];
    const float* wk    = (const float*)d_in[3];
    const float* bk    = (const float*)d_in[4];
    const float* wv    = (const float*)d_in[5];
    const float* bv    = (const float*)d_in[6];
    const float* gamma = (const float*)d_in[7];
    float* out = (float*)d_out;
    float* ws  = (float*)d_ws;

    float*          xp  = ws;                                  // 4,194,304 f32 (16 MB)
    unsigned short* qkb = (unsigned short*)(ws + 4194304);     // 4*4096*64  bf16 (2 MB)
    unsigned short* vtb = qkb + 1048576;                       // 4*256*4096 bf16 (8 MB)
    float*          att = (float*)(vtb + 4194304);             // 4,194,304 f32 (16 MB)

    pool_kernel<<<16384, 256, 0, stream>>>(x, xp);
    proj_kernel<<<1280, 256, 0, stream>>>(xp, wq, bq, wk, bk, wv, bv, qkb, vtb);
    flashm_kernel<<<1024, 256, 0, stream>>>(qkb, vtb, att);
    upsample_kernel<<<65536, 256, 0, stream>>>(att, x, gamma, out);
}